// Round 11
// baseline (349.161 us; speedup 1.0000x reference)
//
#include <hip/hip_runtime.h>
#include <stdint.h>

#define NSEQ 512
#define DDIM 128
#define NROWS (NSEQ * NSEQ)   // 262144
#define PMASK (NROWS - 1)
// Ct plane skew (r9, verified): bijective, 16B-chunk safe.
#define ROT(idx, d) (((idx) + (d) * 128) & PMASK)

typedef __bf16 bf16x8 __attribute__((ext_vector_type(8)));
typedef __bf16 bf16x2v __attribute__((ext_vector_type(2)));
typedef unsigned short u16;
typedef u16 ushort8 __attribute__((ext_vector_type(8)));
typedef float f32x4 __attribute__((ext_vector_type(4)));
typedef uint32_t u32x4 __attribute__((ext_vector_type(4)));
typedef uint32_t u32x2 __attribute__((ext_vector_type(2)));

__device__ __forceinline__ u16 cvt1(float f) {
  return __builtin_bit_cast(u16, (__bf16)f);
}
__device__ __forceinline__ uint32_t pk2(float a, float b) {
  bf16x2v v = {(__bf16)a, (__bf16)b};
  return __builtin_bit_cast(uint32_t, v);
}
__device__ __forceinline__ float bf2f(u16 u) {
  uint32_t x = ((uint32_t)u) << 16;
  return __builtin_bit_cast(float, x);
}
__device__ __forceinline__ f32x4 mfma_bf16(ushort8 a, ushort8 b, f32x4 c) {
  return __builtin_amdgcn_mfma_f32_16x16x32_bf16(
      __builtin_bit_cast(bf16x8, a), __builtin_bit_cast(bf16x8, b), c, 0, 0, 0);
}
__device__ __forceinline__ float sigmoidf_(float x) {
  return __builtin_amdgcn_rcpf(1.0f + __expf(-x));
}

// DPP ROW_ROR rotate (within 16-lane rows), pure-VALU cross-lane
#define ROR16(v, n)                                                            \
  __builtin_bit_cast(float, __builtin_amdgcn_update_dpp(                       \
      __builtin_bit_cast(int, (v)), __builtin_bit_cast(int, (v)),              \
      0x120 + (n), 0xF, 0xF, false))

#define GLOAD16(gp, lp)                                                        \
  __builtin_amdgcn_global_load_lds(                                            \
      (const __attribute__((address_space(1))) void*)(gp),                     \
      (__attribute__((address_space(3))) void*)(lp), 16, 0, 0)

// ---------------------------------------------------------------------------
// K0: weight prep + LN-fold constants.
//  Wb[e][d] = raw[e][d]*niw[d] (raw = [p_in; g_in], e in [0,512))
//  Gb[e][d] = g_out[e][d]*niw[d];  Pb = p_out*now (unchanged); S12 unchanged.
//  C[e]      = sum_d niw[d]*raw[e][d]        (C1, e in [0,512))
//  C[512+e]  = sum_d nib[d]*raw[e][d]        (C2)
//  C[1024+e] = sum_d niw[d]*g_out[e][d]      (C1G, e in [0,128))
//  C[1152+e] = sum_d nib[d]*g_out[e][d]      (C2G)
// ---------------------------------------------------------------------------
__global__ __launch_bounds__(256) void k0_prep(
    const float* __restrict__ p_in_w, const float* __restrict__ g_in_w,
    const float* __restrict__ p_out_w, const float* __restrict__ g_out_w,
    const float* __restrict__ now, const float* __restrict__ nob,
    const float* __restrict__ niw, const float* __restrict__ nib,
    u16* __restrict__ Wb, u16* __restrict__ Pb, u16* __restrict__ Gb,
    float* __restrict__ S12, float* __restrict__ C) {
  const int b = blockIdx.x, t = threadIdx.x;
#pragma unroll
  for (int k = 0; k < 2; ++k) {
    const int idx = b * 512 + k * 256 + t;  // [0, 65536)
    const int d = idx & 127;
    const float v = (idx < 32768) ? p_in_w[idx] : g_in_w[idx - 32768];
    Wb[idx] = cvt1(v * niw[d]);
  }
  if (t < 128) {
    const int idx = b * 128 + t;  // [0, 16384)
    const int d = idx & 127;
    Pb[idx] = cvt1(p_out_w[idx] * now[d]);
    Gb[idx] = cvt1(g_out_w[idx] * niw[d]);
  }
  const int w = t >> 6, lane = t & 63;
  // C1/C2 for e = b*4 + w
  {
    const int e = b * 4 + w;
    const float* src = (e < 256) ? (p_in_w + e * 128) : (g_in_w + (e - 256) * 128);
    const float v0 = src[lane], v1 = src[lane + 64];
    float c1 = niw[lane] * v0 + niw[lane + 64] * v1;
    float c2 = nib[lane] * v0 + nib[lane + 64] * v1;
#pragma unroll
    for (int m = 1; m < 64; m <<= 1) {
      c1 += __shfl_xor(c1, m);
      c2 += __shfl_xor(c2, m);
    }
    if (lane == 0) {
      C[e] = c1;
      C[512 + e] = c2;
    }
  }
  if (w == 0) {  // C1G/C2G for e = b
    const float v0 = g_out_w[b * 128 + lane], v1 = g_out_w[b * 128 + 64 + lane];
    float c1 = niw[lane] * v0 + niw[lane + 64] * v1;
    float c2 = nib[lane] * v0 + nib[lane + 64] * v1;
#pragma unroll
    for (int m = 1; m < 64; m <<= 1) {
      c1 += __shfl_xor(c1, m);
      c2 += __shfl_xor(c2, m);
    }
    if (lane == 0) {
      C[1024 + b] = c1;
      C[1152 + b] = c2;
    }
  }
  if (w == 1) {  // S12 for row b
    const float p0 = p_out_w[b * 128 + lane], p1 = p_out_w[b * 128 + 64 + lane];
    float s1 = p0 * now[lane] + p1 * now[lane + 64];
    float s2 = p0 * nob[lane] + p1 * nob[lane + 64];
#pragma unroll
    for (int m = 1; m < 64; m <<= 1) {
      s1 += __shfl_xor(s1, m);
      s2 += __shfl_xor(s2, m);
    }
    if (lane == 0) {
      S12[2 * b] = s1;
      S12[2 * b + 1] = s2;
    }
  }
}

// ---------------------------------------------------------------------------
// K0b (new): per-row LN stats + raw x -> bf16 cast. One pass over x (vs 4x
// redundant LN in the old k1). stats[r] = {rs, -rs*mu}.
// ---------------------------------------------------------------------------
__global__ __launch_bounds__(256) void k0b_stats(const float* __restrict__ x,
                                                 u16* __restrict__ xbf,
                                                 float* __restrict__ stats) {
  const int tid = threadIdx.x, lane = tid & 63, w = tid >> 6;
  const int g = lane >> 4, c = lane & 15;
  const int r0 = blockIdx.x * 64;
#pragma unroll
  for (int it = 0; it < 4; ++it) {
    const int rl = w * 16 + it * 4 + g;
    const float* xr = x + (size_t)(r0 + rl) * DDIM + c * 8;
    const f32x4 v0 = *(const f32x4*)xr;
    const f32x4 v1 = *(const f32x4*)(xr + 4);
    float s = v0[0] + v0[1] + v0[2] + v0[3] + v1[0] + v1[1] + v1[2] + v1[3];
    float ss = v0[0] * v0[0] + v0[1] * v0[1] + v0[2] * v0[2] + v0[3] * v0[3] +
               v1[0] * v1[0] + v1[1] * v1[1] + v1[2] * v1[2] + v1[3] * v1[3];
    { float t1 = ROR16(s, 1); s += t1; t1 = ROR16(ss, 1); ss += t1; }
    { float t1 = ROR16(s, 2); s += t1; t1 = ROR16(ss, 2); ss += t1; }
    { float t1 = ROR16(s, 4); s += t1; t1 = ROR16(ss, 4); ss += t1; }
    { float t1 = ROR16(s, 8); s += t1; t1 = ROR16(ss, 8); ss += t1; }
    const float mu = s * (1.0f / 128.0f);
    const float rs = rsqrtf(ss * (1.0f / 128.0f) - mu * mu + 1e-5f);
    u32x4 ov{pk2(v0[0], v0[1]), pk2(v0[2], v0[3]), pk2(v1[0], v1[1]),
             pk2(v1[2], v1[3])};
    *(u32x4*)(xbf + (size_t)(r0 + rl) * DDIM + c * 8) = ov;
    if (c == 0) {
      stats[2 * (r0 + rl)] = rs;
      stats[2 * (r0 + rl) + 1] = -rs * mu;
    }
  }
}

// ---------------------------------------------------------------------------
// K1 (restructured): pure GEMM block. xbf staged via global_load_lds with
// pre-swizzled source (k2's verified pattern); LN applied as per-row affine
// in the epilogue (k3's verified fold). Output layout AtB (r10, verified).
// ---------------------------------------------------------------------------
__global__ __launch_bounds__(256, 6) void k1_ln_proj(
    const u16* __restrict__ xbf, const float* __restrict__ mask,
    const float* __restrict__ stats, const float* __restrict__ C,
    const u16* __restrict__ Wb, const u16* __restrict__ Gb,
    u16* __restrict__ AtB, u16* __restrict__ gArg) {
  __shared__ __align__(16) u16 xln[64 * 128];   // 16KB, 16B-granule XOR swizzle
  __shared__ __align__(16) u16 stage[64 * 64];  // 8KB; reused as stage2
  __shared__ float st[128];                     // 64 rows x {rs, t1}
  const int tid = threadIdx.x;
  const int lane = tid & 63;
  const int w = tid >> 6;
  const int bid = blockIdx.x;
  const int rb = (bid >> 5) * 8 + (bid & 7);
  const int cg = (bid >> 3) & 3;
  const int r0 = rb * 64;

  // --- async stage: xbf rows -> swizzled xln (pre-swizzled global source) ---
#pragma unroll
  for (int q = 0; q < 4; ++q) {
    const int idx = q * 256 + tid;  // [0,1024): rl = idx>>4, granule = idx&15
    const int rl = idx >> 4, gg = idx & 15;
    GLOAD16(xbf + (size_t)(r0 + rl) * DDIM + ((gg ^ (rl & 7)) * 8),
            &xln[idx * 8]);
  }
  if (tid < 128) st[tid] = stats[r0 * 2 + tid];
  __syncthreads();

  // --- MFMA pass 1 ---
  const int lr = lane & 15, lq = lane >> 4;
  const int eP = cg * 64 + w * 16;
  const int ecol = eP + lr;
  const float C1p = C[ecol], C2p = C[512 + ecol];
  const float C1q = C[256 + ecol], C2q = C[768 + ecol];
  f32x4 accP[4], accG[4];
#pragma unroll
  for (int m = 0; m < 4; ++m) {
    accP[m] = f32x4{0.f, 0.f, 0.f, 0.f};
    accG[m] = f32x4{0.f, 0.f, 0.f, 0.f};
  }
#pragma unroll
  for (int ks = 0; ks < 4; ++ks) {
    const int kblk = ks * 4 + lq;
    ushort8 af[4];
#pragma unroll
    for (int m = 0; m < 4; ++m) {
      const int row = m * 16 + lr;
      af[m] = *(const ushort8*)((const char*)xln + row * 256 +
                                ((kblk ^ (row & 7)) << 4));
    }
    const int dd = ks * 32 + lq * 8;
    const ushort8 bP = *(const ushort8*)(Wb + ecol * 128 + dd);
    const ushort8 bG = *(const ushort8*)(Wb + (256 + ecol) * 128 + dd);
#pragma unroll
    for (int m = 0; m < 4; ++m) {
      accP[m] = mfma_bf16(af[m], bP, accP[m]);
      accG[m] = mfma_bf16(af[m], bG, accG[m]);
    }
  }

  // --- epilogue: affine-LN + gate + mask -> swizzled LDS stage ---
  const int dloc = w * 16 + lr;
#pragma unroll
  for (int m = 0; m < 4; ++m) {
    const int rloc = m * 16 + lq * 4;
    const f32x4 mv = *(const f32x4*)(mask + r0 + rloc);
    float o[4];
#pragma unroll
    for (int j = 0; j < 4; ++j) {
      const float rs = st[2 * (rloc + j)], t1 = st[2 * (rloc + j) + 1];
      const float hP = rs * accP[m][j] + t1 * C1p + C2p;
      const float hG = rs * accG[m][j] + t1 * C1q + C2q;
      o[j] = hP * sigmoidf_(hG) * mv[j];
    }
    u32x2 pk;
    pk[0] = pk2(o[0], o[1]);
    pk[1] = pk2(o[2], o[3]);
    const int gsw = (m * 4 + lq) ^ (dloc & 15);
    *(u32x2*)((char*)stage + dloc * 128 + (gsw << 3)) = pk;
  }
  __syncthreads();

  // --- write: one contiguous 8KB run AtB[kt][i][cg*64+e][k_in] (r10) ---
  {
    const int i_ = rb >> 3, kt = rb & 7;
    u16* dst = AtB + (((size_t)kt * 512 + i_) * 256 + cg * 64) * 64;
#pragma unroll
    for (int q = 0; q < 2; ++q) {
      const int e = q * 32 + (tid >> 3);
      const int g0 = (tid & 7) * 2;
      const u32x2 lo =
          *(const u32x2*)((const char*)stage + e * 128 + ((g0 ^ (e & 15)) << 3));
      const u32x2 hi = *(const u32x2*)((const char*)stage + e * 128 +
                                       (((g0 + 1) ^ (e & 15)) << 3));
      u32x4 outv{lo[0], lo[1], hi[0], hi[1]};
      *(u32x4*)(dst + e * 64 + (tid & 7) * 8) = outv;
    }
  }

  // --- MFMA pass 2 (cg 0,1): gArg = affine(xln @ Gb^T) ---
  if (cg < 2) {
    f32x4 accO[4];
#pragma unroll
    for (int m = 0; m < 4; ++m) accO[m] = f32x4{0.f, 0.f, 0.f, 0.f};
    const int eg = cg * 64 + w * 16 + lr;
#pragma unroll
    for (int ks = 0; ks < 4; ++ks) {
      const int kblk = ks * 4 + lq;
      const ushort8 bO = *(const ushort8*)(Gb + eg * 128 + ks * 32 + lq * 8);
#pragma unroll
      for (int m = 0; m < 4; ++m) {
        const int row = m * 16 + lr;
        const ushort8 af2 = *(const ushort8*)((const char*)xln + row * 256 +
                                              ((kblk ^ (row & 7)) << 4));
        accO[m] = mfma_bf16(af2, bO, accO[m]);
      }
    }
    __syncthreads();  // done reading `stage` -> safe to alias
    u16* stage2 = stage;
    const float C1Gv = C[1024 + eg], C2Gv = C[1152 + eg];
    const int e_loc = w * 16 + lr;
    const int gsl = e_loc >> 2;
    const int esub = (e_loc & 3) * 2;
#pragma unroll
    for (int m = 0; m < 4; ++m) {
#pragma unroll
      for (int reg = 0; reg < 4; ++reg) {
        const int rl2 = m * 16 + lq * 4 + reg;
        const float rs = st[2 * rl2], t1 = st[2 * rl2 + 1];
        const float val = rs * accO[m][reg] + t1 * C1Gv + C2Gv;
        *(u16*)((char*)stage2 + rl2 * 128 + ((gsl ^ (rl2 & 7)) << 3) + esub) =
            cvt1(val);
      }
    }
    __syncthreads();
#pragma unroll
    for (int p = 0; p < 2; ++p) {
      const int r = p * 32 + (tid >> 3);
      const int il8 = tid & 7;
      const char* base = (const char*)stage2 + r * 128;
      const u32x2 a = *(const u32x2*)(base + (((il8 * 2) ^ (r & 7)) << 3));
      const u32x2 b = *(const u32x2*)(base + (((il8 * 2 + 1) ^ (r & 7)) << 3));
      u32x4 ov{a[0], a[1], b[0], b[1]};
      *(u32x4*)(gArg + (size_t)(r0 + r) * DDIM + cg * 64 + il8 * 8) = ov;
    }
  }
}

// ---------------------------------------------------------------------------
// K2: per-d GEMM from the blocked AtB layout (r10 verbatim).
// ---------------------------------------------------------------------------
__global__ __launch_bounds__(256) void k2_tri(const u16* __restrict__ AtB,
                                              u16* __restrict__ Ct) {
  __shared__ __align__(16) u16 lds[2 * 16384];  // [buf][A:8192 | B:8192] elems
  const int tid = threadIdx.x;
  const int bid = blockIdx.x;
  const int lb = (bid & 7) * 256 + (bid >> 3);
  const int d = lb >> 4;
  const int tile = lb & 15;
  const int i0 = (tile >> 2) * 128, j0 = (tile & 3) * 128;
  const int lane = tid & 63, wid = tid >> 6;
  const int wr = wid >> 1, wc = wid & 1;
  const int lr = lane & 15, lq = lane >> 4;

  f32x4 acc[4][4];
#pragma unroll
  for (int m = 0; m < 4; ++m)
#pragma unroll
    for (int n = 0; n < 4; ++n) acc[m][n] = f32x4{0.f, 0.f, 0.f, 0.f};

  auto stage = [&](int kt, int buf) {
#pragma unroll
    for (int q = 0; q < 4; ++q) {
      const int idx = q * 256 + tid;  // 0..1023
      const int r = idx >> 3, bk = idx & 7;
      const int sbk = bk ^ (r & 7);  // pre-swizzled global source
      GLOAD16(AtB + (((size_t)kt * 512 + i0 + r) * 256 + d) * 64 + sbk * 8,
              &lds[buf * 16384 + idx * 8]);
      GLOAD16(AtB + (((size_t)kt * 512 + j0 + r) * 256 + 128 + d) * 64 + sbk * 8,
              &lds[buf * 16384 + 8192 + idx * 8]);
    }
  };

  stage(0, 0);
  __syncthreads();
  for (int kt = 0; kt < 8; ++kt) {
    const int buf = kt & 1;
    if (kt < 7) stage(kt + 1, buf ^ 1);
    const u16* A_l = &lds[buf * 16384];
    const u16* B_l = &lds[buf * 16384 + 8192];
#pragma unroll
    for (int ks = 0; ks < 2; ++ks) {
      const int kblk = ks * 4 + lq;
      ushort8 af[4], bfr[4];
#pragma unroll
      for (int m = 0; m < 4; ++m) {
        const int row = wr * 64 + m * 16 + lr;
        af[m] = *(const ushort8*)((const char*)A_l + row * 128 +
                                  ((kblk ^ (row & 7)) << 4));
      }
#pragma unroll
      for (int n = 0; n < 4; ++n) {
        const int col = wc * 64 + n * 16 + lr;
        bfr[n] = *(const ushort8*)((const char*)B_l + col * 128 +
                                   ((kblk ^ (col & 7)) << 4));
      }
#pragma unroll
      for (int m = 0; m < 4; ++m)
#pragma unroll
        for (int n = 0; n < 4; ++n)
          acc[m][n] = mfma_bf16(af[m], bfr[n], acc[m][n]);
    }
    __syncthreads();
  }

  u16* Cd = Ct + (size_t)d * NROWS;
#pragma unroll
  for (int m = 0; m < 4; ++m) {
    const int i = i0 + wr * 64 + m * 16 + lq * 4;
#pragma unroll
    for (int n = 0; n < 4; ++n) {
      const int j = j0 + wc * 64 + n * 16 + lr;
#pragma unroll
      for (int reg = 0; reg < 4; ++reg)
        Cd[ROT((i + reg) * NSEQ + j, d)] = cvt1(acc[m][n][reg]);
    }
  }
}

// ---------------------------------------------------------------------------
// K3 (r10 verbatim): out = (rs*(T@P'^T)+affine)*sigmoid(gArg)
// ---------------------------------------------------------------------------
__global__ __launch_bounds__(256, 4) void k3_out(
    const u16* __restrict__ Ct, const u16* __restrict__ gArg,
    const u16* __restrict__ Pb, const float* __restrict__ S12,
    float* __restrict__ out) {
  __shared__ __align__(16) u16 ldsT[128 * 128];  // [r][d], 16B XOR swizzle
  __shared__ float ps[4 * 128], pss[4 * 128];
  __shared__ float prm[128 * 2];
  __shared__ float s12l[128 * 2];
  const int tid = threadIdx.x, lane = tid & 63, w = tid >> 6;
  const int c0 = blockIdx.x * 128;

  {
    const int row2 = lane * 2;
    float s0 = 0.f, ss0 = 0.f, s1 = 0.f, ss1 = 0.f;
#pragma unroll
    for (int db = 0; db < 4; ++db) {
      uint32_t pe[4], po[4];
#pragma unroll
      for (int j = 0; j < 8; ++j) {
        const int d = w * 32 + db * 8 + j;
        const uint32_t v = *(const uint32_t*)(Ct + (size_t)d * NROWS +
                                              ROT(c0 + row2, d));
        const u16 ue = (u16)v, uo = (u16)(v >> 16);
        const float fe = bf2f(ue), fo = bf2f(uo);
        s0 += fe; ss0 += fe * fe;
        s1 += fo; ss1 += fo * fo;
        if (j & 1) {
          pe[j >> 1] |= ((uint32_t)ue) << 16;
          po[j >> 1] |= ((uint32_t)uo) << 16;
        } else {
          pe[j >> 1] = ue;
          po[j >> 1] = uo;
        }
      }
      const int gr = w * 4 + db;
      *(u32x4*)((char*)ldsT + row2 * 256 + ((gr ^ (row2 & 7)) << 4)) =
          u32x4{pe[0], pe[1], pe[2], pe[3]};
      *(u32x4*)((char*)ldsT + (row2 + 1) * 256 + ((gr ^ ((row2 + 1) & 7)) << 4)) =
          u32x4{po[0], po[1], po[2], po[3]};
    }
    ps[w * 128 + row2] = s0;
    pss[w * 128 + row2] = ss0;
    ps[w * 128 + row2 + 1] = s1;
    pss[w * 128 + row2 + 1] = ss1;
  }
  if (tid < 128) ((u32x2*)s12l)[tid] = ((const u32x2*)S12)[tid];
  __syncthreads();
  if (tid < 128) {
    const float s = ps[tid] + ps[128 + tid] + ps[256 + tid] + ps[384 + tid];
    const float ss = pss[tid] + pss[128 + tid] + pss[256 + tid] + pss[384 + tid];
    const float mu = s * (1.f / 128.f);
    const float rs = rsqrtf(ss * (1.f / 128.f) - mu * mu + 1e-5f);
    prm[2 * tid] = rs;
    prm[2 * tid + 1] = -rs * mu;
  }

  const int lr = lane & 15, lq = lane >> 4;
  const int rowbase = w * 32;
  f32x4 aP[2][8];
#pragma unroll
  for (int m = 0; m < 2; ++m)
#pragma unroll
    for (int n = 0; n < 8; ++n) aP[m][n] = f32x4{0.f, 0.f, 0.f, 0.f};
#pragma unroll
  for (int ks = 0; ks < 4; ++ks) {
    const int kblk = ks * 4 + lq;
    ushort8 at2[2];
#pragma unroll
    for (int m = 0; m < 2; ++m) {
      const int row = rowbase + m * 16 + lr;
      at2[m] = *(const ushort8*)((const char*)ldsT + row * 256 +
                                 ((kblk ^ (row & 7)) << 4));
    }
    ushort8 bp[8];
#pragma unroll
    for (int n = 0; n < 8; ++n) {
      const int e = n * 16 + lr;
      bp[n] = *(const ushort8*)(Pb + e * 128 + ks * 32 + lq * 8);
    }
#pragma unroll
    for (int m = 0; m < 2; ++m)
#pragma unroll
      for (int n = 0; n < 8; ++n) aP[m][n] = mfma_bf16(at2[m], bp[n], aP[m][n]);
  }
  __syncthreads();

#pragma unroll
  for (int m = 0; m < 2; ++m) {
    const int crow = rowbase + m * 16 + lq * 4;
#pragma unroll
    for (int n = 0; n < 8; ++n) {
      const int e = n * 16 + lr;
      const float s1 = s12l[2 * e], s2v = s12l[2 * e + 1];
#pragma unroll
      for (int reg = 0; reg < 4; ++reg) {
        const float rs = prm[2 * (crow + reg)];
        const float t1 = prm[2 * (crow + reg) + 1];
        const float op = rs * aP[m][n][reg] + t1 * s1 + s2v;
        const size_t r = (size_t)(c0 + crow + reg);
        const float gt = sigmoidf_(bf2f(gArg[r * DDIM + e]));
        out[r * DDIM + e] = op * gt;
      }
    }
  }
}

// ---------------------------------------------------------------------------
extern "C" void kernel_launch(void* const* d_in, const int* in_sizes, int n_in,
                              void* d_out, int out_size, void* d_ws,
                              size_t ws_size, hipStream_t stream) {
  const float* x = (const float*)d_in[0];
  const float* mask = (const float*)d_in[1];
  const float* niw = (const float*)d_in[2];
  const float* nib = (const float*)d_in[3];
  const float* p_in_w = (const float*)d_in[4];
  const float* g_in_w = (const float*)d_in[5];
  const float* now = (const float*)d_in[6];
  const float* nob = (const float*)d_in[7];
  const float* p_out_w = (const float*)d_in[8];
  const float* g_out_w = (const float*)d_in[9];
  float* out = (float*)d_out;
  char* ws = (char*)d_ws;

  // ws layout (ws_size >= 268633088 proven rounds 3-10)
  u16* AtB = (u16*)(ws);                  // 128 MiB (blocked a|b planes)
  u16* Ct = (u16*)(ws + 134217728);       // 64 MiB
  u16* gA = (u16*)(ws + 201326592);       // 64 MiB
  u16* Wb = (u16*)(ws + 268435456);       // 128 KiB
  u16* Pb = (u16*)(ws + 268566528);       // 32 KiB
  u16* Gb = (u16*)(ws + 268599296);       // 32 KiB
  float* S12 = (float*)(ws + 268632064);  // 1 KiB

  // dead-head of d_out used as scratch (all consumed before k3 writes out):
  u16* xbf = (u16*)d_out;                            // 64 MiB
  float* stats = (float*)((char*)d_out + 67108864);  // 2 MiB
  float* C = (float*)((char*)d_out + 69206016);      // 5 KiB (1280 f32)

  hipLaunchKernelGGL(k0_prep, dim3(128), dim3(256), 0, stream, p_in_w, g_in_w,
                     p_out_w, g_out_w, now, nob, niw, nib, Wb, Pb, Gb, S12, C);
  hipLaunchKernelGGL(k0b_stats, dim3(NROWS / 64), dim3(256), 0, stream, x, xbf,
                     stats);
  hipLaunchKernelGGL(k1_ln_proj, dim3(4 * NROWS / 64), dim3(256), 0, stream,
                     xbf, mask, stats, C, Wb, Gb, AtB, gA);
  hipLaunchKernelGGL(k2_tri, dim3(128 * 16), dim3(256), 0, stream, AtB, Ct);
  hipLaunchKernelGGL(k3_out, dim3(NROWS / 128), dim3(256), 0, stream, Ct, gA,
                     Pb, S12, out);
}